// Round 1
// baseline (253.246 us; speedup 1.0000x reference)
//
#include <hip/hip_runtime.h>
#include <hip/hip_bf16.h>

// Problem constants
#define B 8
#define NH 512
#define NO 512
#define D 128
#define HEADS 4
#define NTOT 1024          // N = NH + NO
#define ALPHA 0.2f

// ---------------- proj1: h1[b,h,n,:] = x[b,n,:] @ W[h], + f1/f2 scalars ----
#define PR 8
__global__ __launch_bounds__(128) void proj1_kernel(
    const float* __restrict__ hs, const float* __restrict__ os,
    const float* __restrict__ W, const float* __restrict__ a,
    float* __restrict__ h1, float* __restrict__ f1, float* __restrict__ f2)
{
    int rt = blockIdx.x;          // row tile: rows rt*8 .. rt*8+7 of 8192
    int h  = blockIdx.y;          // head
    int e  = threadIdx.x;
    int lane = e & 63, wv = e >> 6;
    int row0 = rt * PR;
    int b = row0 >> 10;           // 8 consecutive rows share b (1024 % 8 == 0)

    __shared__ float xs[PR][D];
    #pragma unroll
    for (int r = 0; r < PR; ++r) {
        int n = (row0 + r) & 1023;
        const float* xrow = (n < NH) ? hs + ((size_t)b * NH + n) * D
                                     : os + ((size_t)b * NO + (n - NH)) * D;
        xs[r][e] = xrow[e];
    }
    __syncthreads();

    const float* Wh = W + (size_t)h * D * D;
    float acc[PR];
    #pragma unroll
    for (int r = 0; r < PR; ++r) acc[r] = 0.f;

    for (int d = 0; d < D; d += 4) {
        float w0 = Wh[(d + 0) * D + e];
        float w1 = Wh[(d + 1) * D + e];
        float w2 = Wh[(d + 2) * D + e];
        float w3 = Wh[(d + 3) * D + e];
        #pragma unroll
        for (int r = 0; r < PR; ++r) {
            float4 x4 = *(const float4*)&xs[r][d];
            acc[r] = fmaf(x4.x, w0, acc[r]);
            acc[r] = fmaf(x4.y, w1, acc[r]);
            acc[r] = fmaf(x4.z, w2, acc[r]);
            acc[r] = fmaf(x4.w, w3, acc[r]);
        }
    }

    float a1 = a[h * 256 + e];
    float a2 = a[h * 256 + 128 + e];
    __shared__ float part1[2][PR], part2[2][PR];
    #pragma unroll
    for (int r = 0; r < PR; ++r) {
        int n = (row0 + r) & 1023;
        size_t oi = (((size_t)b * HEADS + h) * NTOT + n) * D + e;
        h1[oi] = acc[r];
        float v1 = acc[r] * a1, v2 = acc[r] * a2;
        #pragma unroll
        for (int o = 32; o > 0; o >>= 1) {
            v1 += __shfl_down(v1, o, 64);
            v2 += __shfl_down(v2, o, 64);
        }
        if (lane == 0) { part1[wv][r] = v1; part2[wv][r] = v2; }
    }
    __syncthreads();
    if (e < PR) {
        int n = (row0 + e) & 1023;
        size_t fi = ((size_t)b * HEADS + h) * NTOT + n;
        f1[fi] = part1[0][e] + part1[1][e];
        f2[fi] = part2[0][e] + part2[1][e];
    }
}

// ---------------- proj2: h2[b,n,:] = x2[b,n,:] @ Wout, + f1b/f2b -----------
__global__ __launch_bounds__(128) void proj2_kernel(
    const float* __restrict__ x2, const float* __restrict__ Wout,
    const float* __restrict__ aout,
    float* __restrict__ h2, float* __restrict__ f1, float* __restrict__ f2)
{
    int rt = blockIdx.x;          // rows rt*8 .. +7 of 8192
    int e  = threadIdx.x;
    int lane = e & 63, wv = e >> 6;
    int row0 = rt * PR;

    __shared__ float xs[PR][512];
    #pragma unroll
    for (int r = 0; r < PR; ++r)
        for (int k = e; k < 512; k += 128)
            xs[r][k] = x2[((size_t)row0 + r) * 512 + k];
    __syncthreads();

    float acc[PR];
    #pragma unroll
    for (int r = 0; r < PR; ++r) acc[r] = 0.f;

    for (int k = 0; k < 512; k += 4) {
        float w0 = Wout[(k + 0) * D + e];
        float w1 = Wout[(k + 1) * D + e];
        float w2 = Wout[(k + 2) * D + e];
        float w3 = Wout[(k + 3) * D + e];
        #pragma unroll
        for (int r = 0; r < PR; ++r) {
            float4 x4 = *(const float4*)&xs[r][k];
            acc[r] = fmaf(x4.x, w0, acc[r]);
            acc[r] = fmaf(x4.y, w1, acc[r]);
            acc[r] = fmaf(x4.z, w2, acc[r]);
            acc[r] = fmaf(x4.w, w3, acc[r]);
        }
    }

    float a1 = aout[e], a2 = aout[128 + e];
    __shared__ float part1[2][PR], part2[2][PR];
    #pragma unroll
    for (int r = 0; r < PR; ++r) {
        size_t oi = ((size_t)row0 + r) * D + e;
        h2[oi] = acc[r];
        float v1 = acc[r] * a1, v2 = acc[r] * a2;
        #pragma unroll
        for (int o = 32; o > 0; o >>= 1) {
            v1 += __shfl_down(v1, o, 64);
            v2 += __shfl_down(v2, o, 64);
        }
        if (lane == 0) { part1[wv][r] = v1; part2[wv][r] = v2; }
    }
    __syncthreads();
    if (e < PR) {
        size_t fi = (size_t)row0 + e;
        f1[fi] = part1[0][e] + part1[1][e];
        f2[fi] = part2[0][e] + part2[1][e];
    }
}

// ---------------- stats: per-row masked softmax max & denom ----------------
// mode 0: layer1, rows = all (bh,n); humans (n<512) attend objects+self,
//         objects attend humans.  grid = 32768.
// mode 1: layer2, rows = humans only (b,n<512), attend objects+self. grid 4096.
__global__ __launch_bounds__(128) void stats_kernel(
    const float* __restrict__ f1, const float* __restrict__ f2,
    float* __restrict__ rm, float* __restrict__ rz, int mode)
{
    int tid = threadIdx.x;
    int gi, nbBase; bool self;
    if (mode == 0) {
        int idx = blockIdx.x;                 // bh*1024 + n
        int n = idx & 1023, bh = idx >> 10;
        self = (n < NH);
        nbBase = bh * NTOT + (self ? NH : 0);
        gi = idx;
    } else {
        int b = blockIdx.x >> 9, n = blockIdx.x & 511;
        gi = b * NTOT + n;
        self = true;
        nbBase = b * NTOT + NH;
    }
    float myf1 = f1[gi];
    __shared__ float s[128];
    float mx = -3e38f;
    for (int j = tid; j < 512; j += 128) {
        float ev = myf1 + f2[nbBase + j];
        ev = ev > 0.f ? ev : ALPHA * ev;
        mx = fmaxf(mx, ev);
    }
    if (self && tid == 0) {
        float ev = myf1 + f2[gi];
        ev = ev > 0.f ? ev : ALPHA * ev;
        mx = fmaxf(mx, ev);
    }
    s[tid] = mx; __syncthreads();
    for (int k = 64; k >= 1; k >>= 1) {
        if (tid < k) s[tid] = fmaxf(s[tid], s[tid + k]);
        __syncthreads();
    }
    float m = s[0];
    __syncthreads();
    float sum = 0.f;
    for (int j = tid; j < 512; j += 128) {
        float ev = myf1 + f2[nbBase + j];
        ev = ev > 0.f ? ev : ALPHA * ev;
        sum += __expf(ev - m);
    }
    if (self && tid == 0) {
        float ev = myf1 + f2[gi];
        ev = ev > 0.f ? ev : ALPHA * ev;
        sum += __expf(ev - m);
    }
    s[tid] = sum; __syncthreads();
    for (int k = 64; k >= 1; k >>= 1) {
        if (tid < k) s[tid] += s[tid + k];
        __syncthreads();
    }
    if (tid == 0) { rm[gi] = m; rz[gi] = s[0]; }
}

// ---------------- attn: out = softmax(e) @ H, tiled ------------------------
// mode 0: layer1. grid (32 tiles, 2 sides, 32 bh). out = x2 (elu applied,
//         [b,n,h*128+e] layout).
// mode 1: layer2 humans. grid (32 tiles, 1, 8 b). out = d_out (elu applied).
#define TI 16
#define TJ 32
__global__ __launch_bounds__(256) void attn_kernel(
    const float* __restrict__ H,
    const float* __restrict__ f1, const float* __restrict__ f2,
    const float* __restrict__ rm, const float* __restrict__ rz,
    float* __restrict__ out, int mode)
{
    int tile = blockIdx.x;
    int t = threadIdx.x;
    int e  = t & 127;
    int ig = t >> 7;

    int bh, side, b, h;
    if (mode == 0) { side = blockIdx.y; bh = blockIdx.z; b = bh >> 2; h = bh & 3; }
    else           { side = 0; bh = blockIdx.z; b = bh; h = 0; }

    int rowLocalBase = side * NH + tile * TI;     // n of first row in tile
    int gRowBase = bh * NTOT + rowLocalBase;      // global feature-row index
    bool hasSelf = (side == 0);
    int nbBase = bh * NTOT + (side == 0 ? NH : 0);

    __shared__ float hb[TJ][D];
    __shared__ float ps[TI][TJ];
    __shared__ float f2nb[512];
    __shared__ float f1c[TI], mC[TI], zC[TI], selfp[TI];

    for (int k = t; k < 512; k += 256) f2nb[k] = f2[nbBase + k];
    if (t < TI) {
        int gi = gRowBase + t;
        float f1v = f1[gi];
        float m   = rm[gi];
        float zi  = 1.f / rz[gi];
        f1c[t] = f1v; mC[t] = m; zC[t] = zi;
        if (hasSelf) {
            float ev = f1v + f2[gi];
            ev = ev > 0.f ? ev : ALPHA * ev;
            selfp[t] = __expf(ev - m) * zi;
        }
    }
    __syncthreads();

    float acc[TI / 2];
    #pragma unroll
    for (int r = 0; r < TI / 2; ++r) acc[r] = 0.f;

    for (int jt = 0; jt < 512 / TJ; ++jt) {
        const float* src = H + ((size_t)nbBase + jt * TJ) * D;
        #pragma unroll
        for (int r = 0; r < TJ * D / 256; ++r) {
            int idx = t + 256 * r;
            ((float*)hb)[idx] = src[idx];
        }
        #pragma unroll
        for (int r = 0; r < TI * TJ / 256; ++r) {
            int idx = t + 256 * r;
            int i = idx >> 5;         // / TJ
            int j = idx & (TJ - 1);
            float ev = f1c[i] + f2nb[jt * TJ + j];
            ev = ev > 0.f ? ev : ALPHA * ev;
            ps[i][j] = __expf(ev - mC[i]) * zC[i];
        }
        __syncthreads();
        #pragma unroll 4
        for (int jj = 0; jj < TJ; ++jj) {
            float hv = hb[jj][e];
            #pragma unroll
            for (int r = 0; r < TI / 2; ++r)
                acc[r] = fmaf(ps[ig * (TI / 2) + r][jj], hv, acc[r]);
        }
        __syncthreads();
    }

    if (hasSelf) {
        #pragma unroll
        for (int r = 0; r < TI / 2; ++r) {
            int i = ig * (TI / 2) + r;
            float hv = H[((size_t)gRowBase + i) * D + e];
            acc[r] = fmaf(selfp[i], hv, acc[r]);
        }
    }

    #pragma unroll
    for (int r = 0; r < TI / 2; ++r) {
        int i = ig * (TI / 2) + r;
        int n = rowLocalBase + i;
        float v = acc[r];
        v = v > 0.f ? v : __expf(v) - 1.f;          // elu
        if (mode == 0)
            out[((size_t)b * NTOT + n) * 512 + h * D + e] = v;
        else
            out[((size_t)b * NH + n) * D + e] = v;
    }
}

// ---------------- log_softmax over features (in-place on d_out) ------------
__global__ __launch_bounds__(128) void lsm_kernel(float* __restrict__ io)
{
    int row = blockIdx.x;                // 0..4095
    int e = threadIdx.x;
    float v = io[(size_t)row * D + e];
    __shared__ float s[128];
    s[e] = v; __syncthreads();
    for (int k = 64; k >= 1; k >>= 1) {
        if (e < k) s[e] = fmaxf(s[e], s[e + k]);
        __syncthreads();
    }
    float m = s[0]; __syncthreads();
    s[e] = __expf(v - m); __syncthreads();
    for (int k = 64; k >= 1; k >>= 1) {
        if (e < k) s[e] += s[e + k];
        __syncthreads();
    }
    float lse = m + __logf(s[0]);
    io[(size_t)row * D + e] = v - lse;
}

extern "C" void kernel_launch(void* const* d_in, const int* in_sizes, int n_in,
                              void* d_out, int out_size, void* d_ws, size_t ws_size,
                              hipStream_t stream)
{
    const float* hs = (const float*)d_in[0];   // [B*NH, D]
    const float* os = (const float*)d_in[1];   // [B*NO, D]
    const float* Wh = (const float*)d_in[4];   // [H, D, D]
    const float* ah = (const float*)d_in[5];   // [H, 2D]
    const float* Wo = (const float*)d_in[6];   // [H*D, D]
    const float* ao = (const float*)d_in[7];   // [2D]
    float* out = (float*)d_out;                // [B*NH, D]
    float* ws = (float*)d_ws;

    float* h1  = ws;                  // 4,194,304 : [B,H,N,D]
    float* x2  = h1  + 4194304;       // 4,194,304 : [B,N,H*D]
    float* h2  = x2  + 4194304;       // 1,048,576 : [B,N,D]
    float* f1a = h2  + 1048576;       // 32768 : [B,H,N]
    float* f2a = f1a + 32768;
    float* rm1 = f2a + 32768;
    float* rz1 = rm1 + 32768;
    float* f1b = rz1 + 32768;         // 8192 : [B,N]
    float* f2b = f1b + 8192;
    float* rm2 = f2b + 8192;
    float* rz2 = rm2 + 8192;

    // Layer 1
    proj1_kernel<<<dim3(1024, HEADS), 128, 0, stream>>>(hs, os, Wh, ah, h1, f1a, f2a);
    stats_kernel<<<32768, 128, 0, stream>>>(f1a, f2a, rm1, rz1, 0);
    attn_kernel<<<dim3(32, 2, 32), 256, 0, stream>>>(h1, f1a, f2a, rm1, rz1, x2, 0);
    // Layer 2
    proj2_kernel<<<1024, 128, 0, stream>>>(x2, Wo, ao, h2, f1b, f2b);
    stats_kernel<<<4096, 128, 0, stream>>>(f1b, f2b, rm2, rz2, 1);
    attn_kernel<<<dim3(32, 1, 8), 256, 0, stream>>>(h2, f1b, f2b, rm2, rz2, out, 1);
    lsm_kernel<<<4096, 128, 0, stream>>>(out);
}

// Round 2
// 204.166 us; speedup vs baseline: 1.2404x; 1.2404x over previous
//
#include <hip/hip_runtime.h>
#include <hip/hip_bf16.h>

// Problem constants
#define B 8
#define NH 512
#define NO 512
#define D 128
#define HEADS 4
#define NTOT 1024
#define ALPHA 0.2f

// ============ proj1: h1[b,h,n,:] = x[b,n,:] @ W[h]; fused f1/f2 ============
// grid (32 row-tiles, 4 heads, 8 b), 256 threads. 4x4 register tile.
__global__ __launch_bounds__(256) void proj1_kernel(
    const float* __restrict__ hs, const float* __restrict__ os,
    const float* __restrict__ W, const float* __restrict__ a,
    float* __restrict__ h1, float* __restrict__ f1, float* __restrict__ f2)
{
    int rt = blockIdx.x, h = blockIdx.y, b = blockIdx.z;
    int t = threadIdx.x;
    int tx = t & 31, ty = t >> 5;          // col group c0=tx*4, row group r0=ty*4

    __shared__ float xT[128][36];          // transposed x tile [k][i]
    __shared__ float wb[32][128];          // W k-chunk [k][c]

    // stage x tile (32 rows x 128 k), transposed into xT
    {
        int i = t >> 3;                    // 0..31
        int k0 = (t & 7) * 16;             // 0..112
        int n = rt * 32 + i;
        const float* xrow = (n < NH) ? hs + ((size_t)b * NH + n) * D
                                     : os + ((size_t)b * NO + (n - NH)) * D;
        float4 v0 = *(const float4*)(xrow + k0);
        float4 v1 = *(const float4*)(xrow + k0 + 4);
        float4 v2 = *(const float4*)(xrow + k0 + 8);
        float4 v3 = *(const float4*)(xrow + k0 + 12);
        float tmp[16] = {v0.x,v0.y,v0.z,v0.w, v1.x,v1.y,v1.z,v1.w,
                         v2.x,v2.y,v2.z,v2.w, v3.x,v3.y,v3.z,v3.w};
        #pragma unroll
        for (int q = 0; q < 16; ++q) xT[k0 + q][i] = tmp[q];
    }

    const float* Wh = W + (size_t)h * D * D;
    float acc[4][4] = {};

    for (int kt = 0; kt < 4; ++kt) {
        __syncthreads();
        // stage W chunk [32 k][128 c]
        {
            int k = t >> 3, c0 = (t & 7) * 16;
            const float* wr = Wh + (size_t)(kt * 32 + k) * D + c0;
            *(float4*)&wb[k][c0]      = *(const float4*)(wr);
            *(float4*)&wb[k][c0 + 4]  = *(const float4*)(wr + 4);
            *(float4*)&wb[k][c0 + 8]  = *(const float4*)(wr + 8);
            *(float4*)&wb[k][c0 + 12] = *(const float4*)(wr + 12);
        }
        __syncthreads();
        #pragma unroll 8
        for (int k = 0; k < 32; ++k) {
            float4 x4 = *(const float4*)&xT[kt * 32 + k][ty * 4];
            float4 w4 = *(const float4*)&wb[k][tx * 4];
            float xr[4] = {x4.x, x4.y, x4.z, x4.w};
            float wc[4] = {w4.x, w4.y, w4.z, w4.w};
            #pragma unroll
            for (int r = 0; r < 4; ++r)
                #pragma unroll
                for (int c = 0; c < 4; ++c)
                    acc[r][c] = fmaf(xr[r], wc[c], acc[r][c]);
        }
    }

    // write h1 + fused f1/f2
    int bh = b * HEADS + h;
    float a1v[4], a2v[4];
    #pragma unroll
    for (int c = 0; c < 4; ++c) {
        a1v[c] = a[h * 256 + tx * 4 + c];
        a2v[c] = a[h * 256 + 128 + tx * 4 + c];
    }
    #pragma unroll
    for (int r = 0; r < 4; ++r) {
        int n = rt * 32 + ty * 4 + r;
        float4 o = {acc[r][0], acc[r][1], acc[r][2], acc[r][3]};
        *(float4*)&h1[((size_t)bh * NTOT + n) * D + tx * 4] = o;
        float v1 = acc[r][0]*a1v[0] + acc[r][1]*a1v[1] + acc[r][2]*a1v[2] + acc[r][3]*a1v[3];
        float v2 = acc[r][0]*a2v[0] + acc[r][1]*a2v[1] + acc[r][2]*a2v[2] + acc[r][3]*a2v[3];
        #pragma unroll
        for (int m = 1; m <= 16; m <<= 1) {
            v1 += __shfl_xor(v1, m, 64);
            v2 += __shfl_xor(v2, m, 64);
        }
        if (tx == 0) {
            f1[(size_t)bh * NTOT + n] = v1;
            f2[(size_t)bh * NTOT + n] = v2;
        }
    }
}

// ============ proj2: h2[g,:] = x2[g,:] @ Wout; fused f1b/f2b ===============
// grid 256 (8192 rows / 32), 256 threads.
__global__ __launch_bounds__(256) void proj2_kernel(
    const float* __restrict__ x2, const float* __restrict__ Wout,
    const float* __restrict__ aout,
    float* __restrict__ h2, float* __restrict__ f1, float* __restrict__ f2)
{
    int rt = blockIdx.x;
    int g0 = rt * 32;
    int t = threadIdx.x;
    int tx = t & 31, ty = t >> 5;

    __shared__ float xTc[32][36];          // transposed x chunk [k][i]
    __shared__ float wb[32][128];

    float acc[4][4] = {};

    for (int kt = 0; kt < 16; ++kt) {
        __syncthreads();
        // stage x chunk transposed: 32 rows x 32 k
        {
            int i = t >> 3, k0 = (t & 7) * 4;
            float4 v = *(const float4*)&x2[((size_t)g0 + i) * 512 + kt * 32 + k0];
            xTc[k0 + 0][i] = v.x;
            xTc[k0 + 1][i] = v.y;
            xTc[k0 + 2][i] = v.z;
            xTc[k0 + 3][i] = v.w;
        }
        // stage W chunk
        {
            int k = t >> 3, c0 = (t & 7) * 16;
            const float* wr = Wout + (size_t)(kt * 32 + k) * D + c0;
            *(float4*)&wb[k][c0]      = *(const float4*)(wr);
            *(float4*)&wb[k][c0 + 4]  = *(const float4*)(wr + 4);
            *(float4*)&wb[k][c0 + 8]  = *(const float4*)(wr + 8);
            *(float4*)&wb[k][c0 + 12] = *(const float4*)(wr + 12);
        }
        __syncthreads();
        #pragma unroll 8
        for (int k = 0; k < 32; ++k) {
            float4 x4 = *(const float4*)&xTc[k][ty * 4];
            float4 w4 = *(const float4*)&wb[k][tx * 4];
            float xr[4] = {x4.x, x4.y, x4.z, x4.w};
            float wc[4] = {w4.x, w4.y, w4.z, w4.w};
            #pragma unroll
            for (int r = 0; r < 4; ++r)
                #pragma unroll
                for (int c = 0; c < 4; ++c)
                    acc[r][c] = fmaf(xr[r], wc[c], acc[r][c]);
        }
    }

    float a1v[4], a2v[4];
    #pragma unroll
    for (int c = 0; c < 4; ++c) {
        a1v[c] = aout[tx * 4 + c];
        a2v[c] = aout[128 + tx * 4 + c];
    }
    #pragma unroll
    for (int r = 0; r < 4; ++r) {
        int g = g0 + ty * 4 + r;
        float4 o = {acc[r][0], acc[r][1], acc[r][2], acc[r][3]};
        *(float4*)&h2[(size_t)g * D + tx * 4] = o;
        float v1 = acc[r][0]*a1v[0] + acc[r][1]*a1v[1] + acc[r][2]*a1v[2] + acc[r][3]*a1v[3];
        float v2 = acc[r][0]*a2v[0] + acc[r][1]*a2v[1] + acc[r][2]*a2v[2] + acc[r][3]*a2v[3];
        #pragma unroll
        for (int m = 1; m <= 16; m <<= 1) {
            v1 += __shfl_xor(v1, m, 64);
            v2 += __shfl_xor(v2, m, 64);
        }
        if (tx == 0) { f1[g] = v1; f2[g] = v2; }
    }
}

// ============ stats: per-row masked softmax max & denom ====================
__global__ __launch_bounds__(128) void stats_kernel(
    const float* __restrict__ f1, const float* __restrict__ f2,
    float* __restrict__ rm, float* __restrict__ rz, int mode)
{
    int tid = threadIdx.x;
    int gi, nbBase; bool self;
    if (mode == 0) {
        int idx = blockIdx.x;
        int n = idx & 1023, bh = idx >> 10;
        self = (n < NH);
        nbBase = bh * NTOT + (self ? NH : 0);
        gi = idx;
    } else {
        int b = blockIdx.x >> 9, n = blockIdx.x & 511;
        gi = b * NTOT + n;
        self = true;
        nbBase = b * NTOT + NH;
    }
    float myf1 = f1[gi];
    __shared__ float s[128];
    float mx = -3e38f;
    for (int j = tid; j < 512; j += 128) {
        float ev = myf1 + f2[nbBase + j];
        ev = ev > 0.f ? ev : ALPHA * ev;
        mx = fmaxf(mx, ev);
    }
    if (self && tid == 0) {
        float ev = myf1 + f2[gi];
        ev = ev > 0.f ? ev : ALPHA * ev;
        mx = fmaxf(mx, ev);
    }
    s[tid] = mx; __syncthreads();
    for (int k = 64; k >= 1; k >>= 1) {
        if (tid < k) s[tid] = fmaxf(s[tid], s[tid + k]);
        __syncthreads();
    }
    float m = s[0];
    __syncthreads();
    float sum = 0.f;
    for (int j = tid; j < 512; j += 128) {
        float ev = myf1 + f2[nbBase + j];
        ev = ev > 0.f ? ev : ALPHA * ev;
        sum += __expf(ev - m);
    }
    if (self && tid == 0) {
        float ev = myf1 + f2[gi];
        ev = ev > 0.f ? ev : ALPHA * ev;
        sum += __expf(ev - m);
    }
    s[tid] = sum; __syncthreads();
    for (int k = 64; k >= 1; k >>= 1) {
        if (tid < k) s[tid] += s[tid + k];
        __syncthreads();
    }
    if (tid == 0) { rm[gi] = m; rz[gi] = s[0]; }
}

// ============ attn: out = softmax(e) @ H, 32-row tile, 4x4 reg tile ========
// mode 0: grid (16, 2, 32); out = x2 [b][n][h*128+c], elu applied.
// mode 1: grid (16, 1, 8);  out = d_out [b*NH+n][c], elu applied.
__global__ __launch_bounds__(256) void attn_kernel(
    const float* __restrict__ H,
    const float* __restrict__ f1, const float* __restrict__ f2,
    const float* __restrict__ rm, const float* __restrict__ rz,
    float* __restrict__ out, int mode)
{
    int tile = blockIdx.x;
    int t = threadIdx.x;
    int tx = t & 31, ty = t >> 5;

    int bh, side, b, h;
    if (mode == 0) { side = blockIdx.y; bh = blockIdx.z; b = bh >> 2; h = bh & 3; }
    else           { side = 0; bh = blockIdx.z; b = bh; h = 0; }

    int rowLocalBase = side * NH + tile * 32;
    int gRowBase = bh * NTOT + rowLocalBase;
    bool hasSelf = (side == 0);
    int nbBase = bh * NTOT + (side == 0 ? NH : 0);

    __shared__ float hb[32][D];            // neighbor features [jj][c]
    __shared__ float pT[32][32];           // attention probs transposed [jj][i]
    __shared__ float f2nb[512];
    __shared__ float f1c[32], mC[32], zC[32], selfp[32];

    for (int k = t; k < 512; k += 256) f2nb[k] = f2[nbBase + k];
    if (t < 32) {
        int gi = gRowBase + t;
        float f1v = f1[gi];
        float m = rm[gi];
        float zi = 1.f / rz[gi];
        f1c[t] = f1v; mC[t] = m; zC[t] = zi;
        if (hasSelf) {
            float ev = f1v + f2[gi];
            ev = ev > 0.f ? ev : ALPHA * ev;
            selfp[t] = __expf(ev - m) * zi;
        }
    }

    float acc[4][4] = {};

    for (int jt = 0; jt < 16; ++jt) {
        __syncthreads();
        // stage 32 neighbor feature rows
        {
            const float4* src = (const float4*)(H + ((size_t)nbBase + jt * 32) * D);
            float4* dst = (float4*)hb;
            dst[t] = src[t];
            dst[t + 256] = src[t + 256];
            dst[t + 512] = src[t + 512];
            dst[t + 768] = src[t + 768];
        }
        // compute probs transposed: thread -> (jj = t>>3, i0 = (t&7)*4)
        {
            int jj = t >> 3, i0 = (t & 7) * 4;
            float f2v = f2nb[jt * 32 + jj];
            float4 pv;
            float* pp = (float*)&pv;
            #pragma unroll
            for (int q = 0; q < 4; ++q) {
                int i = i0 + q;
                float ev = f1c[i] + f2v;
                ev = ev > 0.f ? ev : ALPHA * ev;
                pp[q] = __expf(ev - mC[i]) * zC[i];
            }
            *(float4*)&pT[jj][i0] = pv;
        }
        __syncthreads();
        #pragma unroll 8
        for (int jj = 0; jj < 32; ++jj) {
            float4 p4 = *(const float4*)&pT[jj][ty * 4];
            float4 h4 = *(const float4*)&hb[jj][tx * 4];
            float pr[4] = {p4.x, p4.y, p4.z, p4.w};
            float hc[4] = {h4.x, h4.y, h4.z, h4.w};
            #pragma unroll
            for (int r = 0; r < 4; ++r)
                #pragma unroll
                for (int c = 0; c < 4; ++c)
                    acc[r][c] = fmaf(pr[r], hc[c], acc[r][c]);
        }
    }

    if (hasSelf) {
        #pragma unroll
        for (int r = 0; r < 4; ++r) {
            int i = ty * 4 + r;
            float4 hv = *(const float4*)&H[((size_t)gRowBase + i) * D + tx * 4];
            float sp = selfp[i];
            acc[r][0] = fmaf(sp, hv.x, acc[r][0]);
            acc[r][1] = fmaf(sp, hv.y, acc[r][1]);
            acc[r][2] = fmaf(sp, hv.z, acc[r][2]);
            acc[r][3] = fmaf(sp, hv.w, acc[r][3]);
        }
    }

    #pragma unroll
    for (int r = 0; r < 4; ++r) {
        int n = rowLocalBase + ty * 4 + r;
        float4 v;
        float* vp = (float*)&v;
        #pragma unroll
        for (int c = 0; c < 4; ++c) {
            float x = acc[r][c];
            vp[c] = x > 0.f ? x : __expf(x) - 1.f;   // elu
        }
        if (mode == 0)
            *(float4*)&out[((size_t)b * NTOT + n) * 512 + h * D + tx * 4] = v;
        else
            *(float4*)&out[((size_t)b * NH + n) * D + tx * 4] = v;
    }
}

// ============ log_softmax over features (in-place) =========================
__global__ __launch_bounds__(128) void lsm_kernel(float* __restrict__ io)
{
    int row = blockIdx.x;
    int e = threadIdx.x;
    float v = io[(size_t)row * D + e];
    __shared__ float s[128];
    s[e] = v; __syncthreads();
    for (int k = 64; k >= 1; k >>= 1) {
        if (e < k) s[e] = fmaxf(s[e], s[e + k]);
        __syncthreads();
    }
    float m = s[0]; __syncthreads();
    s[e] = __expf(v - m); __syncthreads();
    for (int k = 64; k >= 1; k >>= 1) {
        if (e < k) s[e] += s[e + k];
        __syncthreads();
    }
    float lse = m + __logf(s[0]);
    io[(size_t)row * D + e] = v - lse;
}

extern "C" void kernel_launch(void* const* d_in, const int* in_sizes, int n_in,
                              void* d_out, int out_size, void* d_ws, size_t ws_size,
                              hipStream_t stream)
{
    const float* hs = (const float*)d_in[0];
    const float* os = (const float*)d_in[1];
    const float* Wh = (const float*)d_in[4];
    const float* ah = (const float*)d_in[5];
    const float* Wo = (const float*)d_in[6];
    const float* ao = (const float*)d_in[7];
    float* out = (float*)d_out;
    float* ws = (float*)d_ws;

    float* h1  = ws;                  // [B,H,N,D]
    float* x2  = h1  + 4194304;       // [B,N,H*D]
    float* h2  = x2  + 4194304;       // [B,N,D]
    float* f1a = h2  + 1048576;       // [B,H,N]
    float* f2a = f1a + 32768;
    float* rm1 = f2a + 32768;
    float* rz1 = rm1 + 32768;
    float* f1b = rz1 + 32768;         // [B,N]
    float* f2b = f1b + 8192;
    float* rm2 = f2b + 8192;
    float* rz2 = rm2 + 8192;

    // Layer 1
    proj1_kernel<<<dim3(32, HEADS, B), 256, 0, stream>>>(hs, os, Wh, ah, h1, f1a, f2a);
    stats_kernel<<<32768, 128, 0, stream>>>(f1a, f2a, rm1, rz1, 0);
    attn_kernel<<<dim3(16, 2, 32), 256, 0, stream>>>(h1, f1a, f2a, rm1, rz1, x2, 0);
    // Layer 2
    proj2_kernel<<<256, 256, 0, stream>>>(x2, Wo, ao, h2, f1b, f2b);
    stats_kernel<<<4096, 128, 0, stream>>>(f1b, f2b, rm2, rz2, 1);
    attn_kernel<<<dim3(16, 1, 8), 256, 0, stream>>>(h2, f1b, f2b, rm2, rz2, out, 1);
    lsm_kernel<<<4096, 128, 0, stream>>>(out);
}

// Round 3
// 96.674 us; speedup vs baseline: 2.6196x; 2.1119x over previous
//
#include <hip/hip_runtime.h>

#define B 8
#define NH 512
#define D 128
#define HEADS 4
#define NTOT 1024
#define ALPHA 0.2f

typedef short short8 __attribute__((ext_vector_type(8)));
typedef float f32x4 __attribute__((ext_vector_type(4)));
typedef unsigned short u16t;

__device__ __forceinline__ unsigned short f2b(float f) {
    union { float f; unsigned u; } v; v.f = f;
    unsigned r = v.u + 0x7FFFu + ((v.u >> 16) & 1u);
    return (unsigned short)(r >> 16);
}
__device__ __forceinline__ float b2f(unsigned short s) {
    union { unsigned u; float f; } v; v.u = ((unsigned)s) << 16;
    return v.f;
}
__device__ __forceinline__ float lrelu(float x) { return fmaxf(x, ALPHA * x); }

// ============ prep: WhT[h][c][k] = Wh[h][k][c], WoT[c][k] = Wo[k][c] ======
__global__ __launch_bounds__(256) void prep_kernel(
    const float* __restrict__ Wh, const float* __restrict__ Wo,
    u16t* __restrict__ WhT, u16t* __restrict__ WoT)
{
    int i = blockIdx.x * 256 + threadIdx.x;          // 0..65535
    {
        int h = i >> 14, rem = i & 16383, c = rem >> 7, k = rem & 127;
        WhT[i] = f2b(Wh[(h * 128 + k) * 128 + c]);
    }
    {
        int c = i >> 9, k = i & 511;
        WoT[i] = f2b(Wo[k * 128 + c]);
    }
}

// ============ proj1: h1T[bh][c][n] = (x @ Wh)^T, + f1a/f2a =================
// grid (128 row-tiles of 64, 4 heads), 256 thr (4 waves, 16 rows each)
__global__ __launch_bounds__(256) void proj1_kernel(
    const float* __restrict__ hs, const float* __restrict__ os,
    const u16t* __restrict__ WhT, const float* __restrict__ ah,
    u16t* __restrict__ h1T, float* __restrict__ f1, float* __restrict__ f2)
{
    int h = blockIdx.y;
    int rowG = blockIdx.x * 64;
    int b = rowG >> 10;
    int t = threadIdx.x;
    int w = t >> 6, l = t & 63, l15 = l & 15, g = l >> 4;

    int nA = (rowG & 1023) + w * 16 + l15;           // A-frag row (local n)
    const float* xr = (nA < NH) ? hs + ((size_t)b * NH + nA) * D
                                : os + ((size_t)b * NH + (nA - NH)) * D;
    const u16t* WTh = WhT + (size_t)h * 128 * 128;

    f32x4 acc[8];
    #pragma unroll
    for (int ct = 0; ct < 8; ++ct) acc[ct] = (f32x4){0.f, 0.f, 0.f, 0.f};

    #pragma unroll
    for (int kc = 0; kc < 4; ++kc) {
        int k0 = kc * 32 + g * 8;
        float4 u0 = *(const float4*)&xr[k0];
        float4 u1 = *(const float4*)&xr[k0 + 4];
        short8 af;
        af[0] = (short)f2b(u0.x); af[1] = (short)f2b(u0.y);
        af[2] = (short)f2b(u0.z); af[3] = (short)f2b(u0.w);
        af[4] = (short)f2b(u1.x); af[5] = (short)f2b(u1.y);
        af[6] = (short)f2b(u1.z); af[7] = (short)f2b(u1.w);
        #pragma unroll
        for (int ct = 0; ct < 8; ++ct) {
            short8 bfr = *(const short8*)&WTh[(ct * 16 + l15) * 128 + k0];
            acc[ct] = __builtin_amdgcn_mfma_f32_16x16x32_bf16(af, bfr, acc[ct], 0, 0, 0);
        }
    }

    int bh = b * HEADS + h;
    size_t hTbase = (size_t)bh * (128 * 1024);
    int nloc0 = (rowG & 1023) + w * 16 + g * 4;      // first of this lane's 4 rows
    float pr1[4] = {0.f, 0.f, 0.f, 0.f}, pr2[4] = {0.f, 0.f, 0.f, 0.f};

    #pragma unroll
    for (int ct = 0; ct < 8; ++ct) {
        int c = ct * 16 + l15;
        unsigned long long pv =
              (unsigned long long)f2b(acc[ct][0])
            | ((unsigned long long)f2b(acc[ct][1]) << 16)
            | ((unsigned long long)f2b(acc[ct][2]) << 32)
            | ((unsigned long long)f2b(acc[ct][3]) << 48);
        *(unsigned long long*)&h1T[hTbase + (size_t)c * 1024 + nloc0] = pv;
        float a1 = ah[h * 256 + c], a2 = ah[h * 256 + 128 + c];
        #pragma unroll
        for (int r = 0; r < 4; ++r) {
            pr1[r] = fmaf(acc[ct][r], a1, pr1[r]);
            pr2[r] = fmaf(acc[ct][r], a2, pr2[r]);
        }
    }
    #pragma unroll
    for (int r = 0; r < 4; ++r) {
        float v1 = pr1[r], v2 = pr2[r];
        #pragma unroll
        for (int m = 1; m <= 8; m <<= 1) {
            v1 += __shfl_xor(v1, m, 64);
            v2 += __shfl_xor(v2, m, 64);
        }
        if (l15 == 0) {
            f1[(size_t)bh * 1024 + nloc0 + r] = v1;
            f2[(size_t)bh * 1024 + nloc0 + r] = v2;
        }
    }
}

// ============ proj2: h2T[b][c][n] = (x2 @ Wo)^T, + f1b/f2b =================
// grid (128 row-tiles of 64), 256 thr. x2 is bf16 row-major [8192][512].
__global__ __launch_bounds__(256) void proj2_kernel(
    const u16t* __restrict__ x2, const u16t* __restrict__ WoT,
    const float* __restrict__ ao,
    u16t* __restrict__ h2T, float* __restrict__ f1, float* __restrict__ f2)
{
    int rowG = blockIdx.x * 64;
    int b = rowG >> 10;
    int t = threadIdx.x;
    int w = t >> 6, l = t & 63, l15 = l & 15, g = l >> 4;

    int rowA = rowG + w * 16 + l15;

    f32x4 acc[8];
    #pragma unroll
    for (int ct = 0; ct < 8; ++ct) acc[ct] = (f32x4){0.f, 0.f, 0.f, 0.f};

    #pragma unroll
    for (int kc = 0; kc < 16; ++kc) {
        int k0 = kc * 32 + g * 8;
        short8 af = *(const short8*)&x2[(size_t)rowA * 512 + k0];
        #pragma unroll
        for (int ct = 0; ct < 8; ++ct) {
            short8 bfr = *(const short8*)&WoT[(ct * 16 + l15) * 512 + k0];
            acc[ct] = __builtin_amdgcn_mfma_f32_16x16x32_bf16(af, bfr, acc[ct], 0, 0, 0);
        }
    }

    size_t hTbase = (size_t)b * (128 * 1024);
    int nloc0 = (rowG & 1023) + w * 16 + g * 4;
    int rowOut0 = rowG + w * 16 + g * 4;
    float pr1[4] = {0.f, 0.f, 0.f, 0.f}, pr2[4] = {0.f, 0.f, 0.f, 0.f};

    #pragma unroll
    for (int ct = 0; ct < 8; ++ct) {
        int c = ct * 16 + l15;
        unsigned long long pv =
              (unsigned long long)f2b(acc[ct][0])
            | ((unsigned long long)f2b(acc[ct][1]) << 16)
            | ((unsigned long long)f2b(acc[ct][2]) << 32)
            | ((unsigned long long)f2b(acc[ct][3]) << 48);
        *(unsigned long long*)&h2T[hTbase + (size_t)c * 1024 + nloc0] = pv;
        float a1 = ao[c], a2 = ao[128 + c];
        #pragma unroll
        for (int r = 0; r < 4; ++r) {
            pr1[r] = fmaf(acc[ct][r], a1, pr1[r]);
            pr2[r] = fmaf(acc[ct][r], a2, pr2[r]);
        }
    }
    #pragma unroll
    for (int r = 0; r < 4; ++r) {
        float v1 = pr1[r], v2 = pr2[r];
        #pragma unroll
        for (int m = 1; m <= 8; m <<= 1) {
            v1 += __shfl_xor(v1, m, 64);
            v2 += __shfl_xor(v2, m, 64);
        }
        if (l15 == 0) {
            f1[rowOut0 + r] = v1;
            f2[rowOut0 + r] = v2;
        }
    }
}

// ============ attn: O^T = H^T · P^T (MFMA), fused softmax-z + epilogue =====
// mode 0: grid (4 itiles, 2 sides, 32 bh), out = x2 bf16 [8192][512] (+elu)
// mode 1: grid (4 itiles, 1, 8 b),  out = d_out f32 (+elu +log_softmax)
__global__ __launch_bounds__(256) void attn_kernel(
    const u16t* __restrict__ HT,                 // [Z][128][1024] bf16
    const float* __restrict__ f1, const float* __restrict__ f2,   // [Z][1024]
    u16t* __restrict__ x2, float* __restrict__ dout, int mode)
{
    __shared__ __align__(16) u16t hbuf[2][128][40];   // [buf][c][k-pad]
    __shared__ __align__(16) float f2s[512];
    __shared__ float red[256];

    int t = threadIdx.x, w = t >> 6, l = t & 63, l15 = l & 15, g = l >> 4;
    int itile = blockIdx.x;
    int side = (mode == 0) ? blockIdx.y : 0;
    int z = blockIdx.z;
    int b = (mode == 0) ? (z >> 2) : z;
    int h = (mode == 0) ? (z & 3) : 0;
    bool self = (side == 0);
    int nbBase = self ? 512 : 0;
    size_t HTbase = (size_t)z * (128 * 1024);
    size_t fbase = (size_t)z * 1024;

    // stage neighbor f2 + block max M
    f2s[t] = f2[fbase + nbBase + t];
    f2s[t + 256] = f2[fbase + nbBase + t + 256];
    __syncthreads();
    red[t] = fmaxf(f2s[t], f2s[t + 256]);
    __syncthreads();
    for (int k = 128; k >= 1; k >>= 1) {
        if (t < k) red[t] = fmaxf(red[t], red[t + k]);
        __syncthreads();
    }
    float M = red[0];

    // per-lane row stats (lane owns rows i0w + bf*16 + l15)
    int i0w = itile * 128 + w * 32;
    float f1v[2], mrow[2], zacc[2], z0[2];
    #pragma unroll
    for (int bf = 0; bf < 2; ++bf) {
        int i = i0w + bf * 16 + l15;
        int n = side * 512 + i;
        float fv = f1[fbase + n];
        f1v[bf] = fv;
        float mr = lrelu(fv + M);
        float zz = 0.f;
        if (self) {
            float sc = lrelu(fv + f2[fbase + i]);
            mr = fmaxf(mr, sc);
            zz = __expf(sc - mr);
        }
        mrow[bf] = mr; zacc[bf] = zz; z0[bf] = zz;
    }

    // prologue: stage chunk 0
    {
        int c = t >> 1, ks = (t & 1) * 16;
        const u16t* src = &HT[HTbase + (size_t)c * 1024 + nbBase + ks];
        *(short8*)&hbuf[0][c][ks] = *(const short8*)src;
        *(short8*)&hbuf[0][c][ks + 8] = *(const short8*)(src + 8);
    }
    __syncthreads();

    f32x4 acc[8][2];
    #pragma unroll
    for (int ct = 0; ct < 8; ++ct) {
        acc[ct][0] = (f32x4){0.f, 0.f, 0.f, 0.f};
        acc[ct][1] = (f32x4){0.f, 0.f, 0.f, 0.f};
    }

    int cS = t >> 1, ksS = (t & 1) * 16;
    for (int jt = 0; jt < 16; ++jt) {
        int cur = jt & 1;
        // prefetch next chunk to regs
        short8 s0, s1;
        if (jt < 15) {
            const u16t* src = &HT[HTbase + (size_t)cS * 1024 + nbBase + (jt + 1) * 32 + ksS];
            s0 = *(const short8*)src;
            s1 = *(const short8*)(src + 8);
        }
        // P fragments (B-operand), on the fly
        short8 pf[2];
        int j0 = jt * 32 + g * 8;
        float4 fa = *(const float4*)&f2s[j0];
        float4 fb4 = *(const float4*)&f2s[j0 + 4];
        float fj[8] = {fa.x, fa.y, fa.z, fa.w, fb4.x, fb4.y, fb4.z, fb4.w};
        #pragma unroll
        for (int bf = 0; bf < 2; ++bf) {
            float zs = 0.f;
            #pragma unroll
            for (int j = 0; j < 8; ++j) {
                float ev = lrelu(f1v[bf] + fj[j]);
                float p = __expf(ev - mrow[bf]);
                zs += p;
                pf[bf][j] = (short)f2b(p);
            }
            zacc[bf] += zs;
        }
        // MFMA over 8 feature tiles
        #pragma unroll
        for (int ct = 0; ct < 8; ++ct) {
            short8 hf = *(const short8*)&hbuf[cur][ct * 16 + l15][g * 8];
            acc[ct][0] = __builtin_amdgcn_mfma_f32_16x16x32_bf16(hf, pf[0], acc[ct][0], 0, 0, 0);
            acc[ct][1] = __builtin_amdgcn_mfma_f32_16x16x32_bf16(hf, pf[1], acc[ct][1], 0, 0, 0);
        }
        // write prefetched chunk to other buffer, then single barrier
        if (jt < 15) {
            *(short8*)&hbuf[cur ^ 1][cS][ksS] = s0;
            *(short8*)&hbuf[cur ^ 1][cS][ksS + 8] = s1;
        }
        __syncthreads();
    }

    // z reduction across k-groups (lane's cols match its P rows)
    #pragma unroll
    for (int bf = 0; bf < 2; ++bf) {
        zacc[bf] += __shfl_xor(zacc[bf], 16, 64);
        zacc[bf] += __shfl_xor(zacc[bf], 32, 64);
    }
    float zinv[2] = {1.f / zacc[0], 1.f / zacc[1]};

    if (mode == 0) {
        #pragma unroll
        for (int bf = 0; bf < 2; ++bf) {
            int i = i0w + bf * 16 + l15;
            int n = side * 512 + i;
            size_t orow = ((size_t)(b * 1024 + n)) * 512 + h * 128;
            #pragma unroll
            for (int ct = 0; ct < 8; ++ct) {
                int c0 = ct * 16 + g * 4;
                float o[4];
                #pragma unroll
                for (int r = 0; r < 4; ++r) {
                    float v = acc[ct][bf][r];
                    if (self) v = fmaf(z0[bf], b2f(HT[HTbase + (size_t)(c0 + r) * 1024 + i]), v);
                    v *= zinv[bf];
                    o[r] = v > 0.f ? v : __expf(v) - 1.f;
                }
                unsigned long long pv =
                      (unsigned long long)f2b(o[0])
                    | ((unsigned long long)f2b(o[1]) << 16)
                    | ((unsigned long long)f2b(o[2]) << 32)
                    | ((unsigned long long)f2b(o[3]) << 48);
                *(unsigned long long*)&x2[orow + c0] = pv;
            }
        }
    } else {
        #pragma unroll
        for (int bf = 0; bf < 2; ++bf) {
            int i = i0w + bf * 16 + l15;
            float o[8][4];
            float mx = -3.0e38f;
            #pragma unroll
            for (int ct = 0; ct < 8; ++ct) {
                int c0 = ct * 16 + g * 4;
                #pragma unroll
                for (int r = 0; r < 4; ++r) {
                    float v = acc[ct][bf][r];
                    v = fmaf(z0[bf], b2f(HT[HTbase + (size_t)(c0 + r) * 1024 + i]), v);
                    v *= zinv[bf];
                    v = v > 0.f ? v : __expf(v) - 1.f;   // elu
                    o[ct][r] = v;
                    mx = fmaxf(mx, v);
                }
            }
            mx = fmaxf(mx, __shfl_xor(mx, 16, 64));
            mx = fmaxf(mx, __shfl_xor(mx, 32, 64));
            float s = 0.f;
            #pragma unroll
            for (int ct = 0; ct < 8; ++ct)
                #pragma unroll
                for (int r = 0; r < 4; ++r) s += __expf(o[ct][r] - mx);
            s += __shfl_xor(s, 16, 64);
            s += __shfl_xor(s, 32, 64);
            float lse = mx + __logf(s);
            #pragma unroll
            for (int ct = 0; ct < 8; ++ct) {
                float4 st = {o[ct][0] - lse, o[ct][1] - lse, o[ct][2] - lse, o[ct][3] - lse};
                *(float4*)&dout[((size_t)(b * 512 + i)) * 128 + ct * 16 + g * 4] = st;
            }
        }
    }
}

extern "C" void kernel_launch(void* const* d_in, const int* in_sizes, int n_in,
                              void* d_out, int out_size, void* d_ws, size_t ws_size,
                              hipStream_t stream)
{
    const float* hs = (const float*)d_in[0];
    const float* os = (const float*)d_in[1];
    const float* Wh = (const float*)d_in[4];
    const float* ah = (const float*)d_in[5];
    const float* Wo = (const float*)d_in[6];
    const float* ao = (const float*)d_in[7];
    float* out = (float*)d_out;

    u16t* h1T = (u16t*)d_ws;            // 32*128*1024 = 4,194,304 bf16
    u16t* x2  = h1T + 4194304;          // 8192*512
    u16t* h2T = x2 + 4194304;           // 8*128*1024 = 1,048,576
    u16t* WhT = h2T + 1048576;          // 65536
    u16t* WoT = WhT + 65536;            // 65536
    float* f1a = (float*)(WoT + 65536); // 32768
    float* f2a = f1a + 32768;
    float* f1b = f2a + 32768;           // 8192
    float* f2b = f1b + 8192;

    prep_kernel<<<256, 256, 0, stream>>>(Wh, Wo, WhT, WoT);
    proj1_kernel<<<dim3(128, HEADS), 256, 0, stream>>>(hs, os, WhT, ah, h1T, f1a, f2a);
    attn_kernel<<<dim3(4, 2, 32), 256, 0, stream>>>(h1T, f1a, f2a, x2, nullptr, 0);
    proj2_kernel<<<dim3(128, 1), 256, 0, stream>>>(x2, WoT, ao, h2T, f1b, f2b);
    attn_kernel<<<dim3(4, 1, 8), 256, 0, stream>>>(h2T, f1b, f2b, nullptr, out, 1);
}

// Round 4
// 72.492 us; speedup vs baseline: 3.4934x; 1.3336x over previous
//
#include <hip/hip_runtime.h>

#define B 8
#define NH 512
#define D 128
#define HEADS 4
#define ALPHA 0.2f

typedef short short8 __attribute__((ext_vector_type(8)));
typedef float f32x4 __attribute__((ext_vector_type(4)));
typedef unsigned short u16t;

__device__ __forceinline__ unsigned short f2b(float f) {
    union { float f; unsigned u; } v; v.f = f;
    unsigned r = v.u + 0x7FFFu + ((v.u >> 16) & 1u);
    return (unsigned short)(r >> 16);
}
__device__ __forceinline__ float lrelu(float x) { return fmaxf(x, ALPHA * x); }
// pack two f32 -> two bf16 (truncation) in one v_perm
__device__ __forceinline__ unsigned packbf(float a, float b) {
    union { float f; unsigned u; } ua, ub; ua.f = a; ub.f = b;
    return __builtin_amdgcn_perm(ub.u, ua.u, 0x07060302u);
}

// ============ prep: transpose+cvt weights, cvt x to bf16 ===================
// WhT[h][c][k], WoT[c][k], xb[b*1024+n][k]
__global__ __launch_bounds__(256) void prep_kernel(
    const float* __restrict__ hs, const float* __restrict__ os,
    const float* __restrict__ Wh, const float* __restrict__ Wo,
    u16t* __restrict__ WhT, u16t* __restrict__ WoT, u16t* __restrict__ xb)
{
    int i = blockIdx.x * 256 + threadIdx.x;          // 0..65535
    {
        int h = i >> 14, rem = i & 16383, c = rem >> 7, k = rem & 127;
        WhT[i] = f2b(Wh[(h * 128 + k) * 128 + c]);
    }
    {
        int c = i >> 9, k = i & 511;
        WoT[i] = f2b(Wo[k * 128 + c]);
    }
    {
        size_t base = (size_t)i * 16;                // 16 elems, same row
        int row = (int)(base >> 7);                  // 0..8191
        int col = (int)(base & 127);
        int b = row >> 10, n = row & 1023;
        const float* src = (n < NH) ? hs + ((size_t)(b * NH + n)) * 128 + col
                                    : os + ((size_t)(b * NH + (n - NH))) * 128 + col;
        u16t* dst = xb + base;
        #pragma unroll
        for (int q = 0; q < 16; q += 4) {
            float4 v = *(const float4*)(src + q);
            dst[q + 0] = f2b(v.x); dst[q + 1] = f2b(v.y);
            dst[q + 2] = f2b(v.z); dst[q + 3] = f2b(v.w);
        }
    }
}

// ============ proj1: h1T[bh][c][n] = (x @ Wh)^T, + f1a/f2a =================
// grid (128 row-tiles of 64, 4 heads), 256 thr
__global__ __launch_bounds__(256) void proj1_kernel(
    const u16t* __restrict__ xb, const u16t* __restrict__ WhT,
    const float* __restrict__ ah,
    u16t* __restrict__ h1T, float* __restrict__ f1, float* __restrict__ f2)
{
    int h = blockIdx.y;
    int rowG = blockIdx.x * 64;                      // global row base
    int b = rowG >> 10;
    int t = threadIdx.x;
    int w = t >> 6, l = t & 63, l15 = l & 15, g = l >> 4;

    int nA = rowG + w * 16 + l15;                    // A-frag global row
    const u16t* WTh = WhT + (size_t)h * 16384;

    f32x4 acc[8] = {};

    #pragma unroll
    for (int kc = 0; kc < 4; ++kc) {
        int k0 = kc * 32 + g * 8;
        short8 af = *(const short8*)&xb[(size_t)nA * 128 + k0];
        #pragma unroll
        for (int ct = 0; ct < 8; ++ct) {
            short8 bfr = *(const short8*)&WTh[(ct * 16 + l15) * 128 + k0];
            acc[ct] = __builtin_amdgcn_mfma_f32_16x16x32_bf16(af, bfr, acc[ct], 0, 0, 0);
        }
    }

    int bh = b * HEADS + h;
    size_t hTbase = (size_t)bh * 131072;
    int nloc0 = (rowG & 1023) + w * 16 + g * 4;
    float pr1[4] = {0.f, 0.f, 0.f, 0.f}, pr2[4] = {0.f, 0.f, 0.f, 0.f};

    #pragma unroll
    for (int ct = 0; ct < 8; ++ct) {
        int c = ct * 16 + l15;
        unsigned long long pv =
              (unsigned long long)f2b(acc[ct][0])
            | ((unsigned long long)f2b(acc[ct][1]) << 16)
            | ((unsigned long long)f2b(acc[ct][2]) << 32)
            | ((unsigned long long)f2b(acc[ct][3]) << 48);
        *(unsigned long long*)&h1T[hTbase + (size_t)c * 1024 + nloc0] = pv;
        float a1 = ah[h * 256 + c], a2 = ah[h * 256 + 128 + c];
        #pragma unroll
        for (int r = 0; r < 4; ++r) {
            pr1[r] = fmaf(acc[ct][r], a1, pr1[r]);
            pr2[r] = fmaf(acc[ct][r], a2, pr2[r]);
        }
    }
    #pragma unroll
    for (int r = 0; r < 4; ++r) {
        float v1 = pr1[r], v2 = pr2[r];
        #pragma unroll
        for (int m = 1; m <= 8; m <<= 1) {
            v1 += __shfl_xor(v1, m, 64);
            v2 += __shfl_xor(v2, m, 64);
        }
        if (l15 == 0) {
            f1[(size_t)bh * 1024 + nloc0 + r] = v1;
            f2[(size_t)bh * 1024 + nloc0 + r] = v2;
        }
    }
}

// ============ proj2: h2T[b][c][n] = (x2 @ Wo)^T, + f1b/f2b =================
// grid 128 (8192 rows / 64), 256 thr. x2 bf16 row-major [8192][512].
__global__ __launch_bounds__(256) void proj2_kernel(
    const u16t* __restrict__ x2, const u16t* __restrict__ WoT,
    const float* __restrict__ ao,
    u16t* __restrict__ h2T, float* __restrict__ f1, float* __restrict__ f2)
{
    int rowG = blockIdx.x * 64;
    int b = rowG >> 10;
    int t = threadIdx.x;
    int w = t >> 6, l = t & 63, l15 = l & 15, g = l >> 4;

    int rowA = rowG + w * 16 + l15;

    f32x4 acc[8] = {};

    #pragma unroll
    for (int kc = 0; kc < 16; ++kc) {
        int k0 = kc * 32 + g * 8;
        short8 af = *(const short8*)&x2[(size_t)rowA * 512 + k0];
        #pragma unroll
        for (int ct = 0; ct < 8; ++ct) {
            short8 bfr = *(const short8*)&WoT[(ct * 16 + l15) * 512 + k0];
            acc[ct] = __builtin_amdgcn_mfma_f32_16x16x32_bf16(af, bfr, acc[ct], 0, 0, 0);
        }
    }

    size_t hTbase = (size_t)b * 131072;
    int nloc0 = (rowG & 1023) + w * 16 + g * 4;
    int rowOut0 = rowG + w * 16 + g * 4;
    float pr1[4] = {0.f, 0.f, 0.f, 0.f}, pr2[4] = {0.f, 0.f, 0.f, 0.f};

    #pragma unroll
    for (int ct = 0; ct < 8; ++ct) {
        int c = ct * 16 + l15;
        unsigned long long pv =
              (unsigned long long)f2b(acc[ct][0])
            | ((unsigned long long)f2b(acc[ct][1]) << 16)
            | ((unsigned long long)f2b(acc[ct][2]) << 32)
            | ((unsigned long long)f2b(acc[ct][3]) << 48);
        *(unsigned long long*)&h2T[hTbase + (size_t)c * 1024 + nloc0] = pv;
        float a1 = ao[c], a2 = ao[128 + c];
        #pragma unroll
        for (int r = 0; r < 4; ++r) {
            pr1[r] = fmaf(acc[ct][r], a1, pr1[r]);
            pr2[r] = fmaf(acc[ct][r], a2, pr2[r]);
        }
    }
    #pragma unroll
    for (int r = 0; r < 4; ++r) {
        float v1 = pr1[r], v2 = pr2[r];
        #pragma unroll
        for (int m = 1; m <= 8; m <<= 1) {
            v1 += __shfl_xor(v1, m, 64);
            v2 += __shfl_xor(v2, m, 64);
        }
        if (l15 == 0) { f1[rowOut0 + r] = v1; f2[rowOut0 + r] = v2; }
    }
}

// ============ attn: O^T = H^T · P^T (MFMA), self via diagonal MFMA =========
// mode 0: 512 blocks (XCD-swizzled: 64 q=(z,side) x 8 itiles of 64 rows)
// mode 1: 64 blocks (8 b x 8 itiles), + fused elu+log_softmax
__global__ __launch_bounds__(256) void attn_kernel(
    const u16t* __restrict__ HT,                    // [Z][128][1024] bf16
    const float* __restrict__ f1, const float* __restrict__ f2,  // [Z][1024]
    u16t* __restrict__ x2, float* __restrict__ dout, int mode)
{
    __shared__ __align__(16) u16t hbuf[2][128][40];
    __shared__ __align__(16) float f2s[512];
    __shared__ float red4[4];

    int t = threadIdx.x, w4 = t >> 6, l = t & 63, l15 = l & 15, g = l >> 4;
    int wid = blockIdx.x;
    int itile, side, z, b, h;
    if (mode == 0) {
        int xcd = wid & 7, jj = (wid >> 3) & 7;
        itile = wid >> 6;
        int q = xcd * 8 + jj;                       // all itiles of q share XCD
        z = q >> 1; side = q & 1; b = z >> 2; h = z & 3;
    } else {
        b = wid & 7; itile = wid >> 3; side = 0; z = b; h = 0;
    }
    bool self = (side == 0);
    int nbBase = self ? 512 : 0;
    size_t HTbase = (size_t)z * 131072;
    size_t fbase = (size_t)z * 1024;

    // stage neighbor f2 + block max M
    f2s[t] = f2[fbase + nbBase + t];
    f2s[t + 256] = f2[fbase + nbBase + t + 256];
    __syncthreads();
    float mv = fmaxf(f2s[t], f2s[t + 256]);
    #pragma unroll
    for (int m = 1; m <= 32; m <<= 1) mv = fmaxf(mv, __shfl_xor(mv, m, 64));
    if (l == 0) red4[w4] = mv;
    __syncthreads();
    float M = fmaxf(fmaxf(red4[0], red4[1]), fmaxf(red4[2], red4[3]));

    // per-lane row stats: wave owns 16 rows i0..i0+15, lane's row = i0+l15
    int i0 = itile * 64 + w4 * 16;
    int i = i0 + l15;
    int n = side * 512 + i;
    float fv = f1[fbase + n];
    float mr = lrelu(fv + M);
    float z0 = 0.f;
    if (self) {
        float sc = lrelu(fv + f2[fbase + i]);
        mr = fmaxf(mr, sc);
        z0 = __expf(sc - mr);
    }
    float zacc = (g == 0) ? z0 : 0.f;               // count self exactly once

    // prologue: stage chunk 0
    {
        int c = t >> 1, ks = (t & 1) * 16;
        const u16t* src = &HT[HTbase + (size_t)c * 1024 + nbBase + ks];
        *(short8*)&hbuf[0][c][ks] = *(const short8*)src;
        *(short8*)&hbuf[0][c][ks + 8] = *(const short8*)(src + 8);
    }
    __syncthreads();

    f32x4 acc[8] = {};
    int cS = t >> 1, ksS = (t & 1) * 16;

    for (int jt = 0; jt < 16; ++jt) {
        int cur = jt & 1;
        short8 s0, s1;
        if (jt < 15) {
            const u16t* src = &HT[HTbase + (size_t)cS * 1024 + nbBase + (jt + 1) * 32 + ksS];
            s0 = *(const short8*)src;
            s1 = *(const short8*)(src + 8);
        }
        // P fragment for this wave's 16 rows x 8 j-slots
        int j0 = jt * 32 + g * 8;
        float p[8];
        #pragma unroll
        for (int q = 0; q < 8; ++q) {
            float tq = fv + f2s[j0 + q];
            float ev = fmaxf(tq, ALPHA * tq);
            p[q] = __expf(ev - mr);
            zacc += p[q];
        }
        union { unsigned u[4]; short8 s; } pfu;
        pfu.u[0] = packbf(p[0], p[1]);
        pfu.u[1] = packbf(p[2], p[3]);
        pfu.u[2] = packbf(p[4], p[5]);
        pfu.u[3] = packbf(p[6], p[7]);
        short8 pf = pfu.s;
        #pragma unroll
        for (int ct = 0; ct < 8; ++ct) {
            short8 hf = *(const short8*)&hbuf[cur][ct * 16 + l15][g * 8];
            acc[ct] = __builtin_amdgcn_mfma_f32_16x16x32_bf16(hf, pf, acc[ct], 0, 0, 0);
        }
        if (jt < 15) {
            *(short8*)&hbuf[cur ^ 1][cS][ksS] = s0;
            *(short8*)&hbuf[cur ^ 1][cS][ksS + 8] = s1;
        }
        __syncthreads();
    }

    // self-loop term as one diagonal-B MFMA per ct (no scalar loads)
    if (self) {
        unsigned short z0b = f2b(z0);
        short8 pfs;
        #pragma unroll
        for (int q = 0; q < 8; ++q)
            pfs[q] = (short)((g * 8 + q == l15) ? z0b : 0);
        int sc0 = side * 512 + i0;                  // self-column base
        #pragma unroll
        for (int ct = 0; ct < 8; ++ct) {
            short8 hfs = *(const short8*)&HT[HTbase + (size_t)(ct * 16 + l15) * 1024 + sc0 + g * 8];
            acc[ct] = __builtin_amdgcn_mfma_f32_16x16x32_bf16(hfs, pfs, acc[ct], 0, 0, 0);
        }
    }

    // z across the 4 k-groups
    zacc += __shfl_xor(zacc, 16, 64);
    zacc += __shfl_xor(zacc, 32, 64);
    float zinv = 1.f / zacc;

    if (mode == 0) {
        size_t orow = ((size_t)(b * 1024 + n)) * 512 + h * 128;
        #pragma unroll
        for (int ct = 0; ct < 8; ++ct) {
            int c0 = ct * 16 + g * 4;
            float o[4];
            #pragma unroll
            for (int r = 0; r < 4; ++r) {
                float v = acc[ct][r] * zinv;
                o[r] = v > 0.f ? v : __expf(v) - 1.f;
            }
            unsigned long long pv =
                  (unsigned long long)f2b(o[0])
                | ((unsigned long long)f2b(o[1]) << 16)
                | ((unsigned long long)f2b(o[2]) << 32)
                | ((unsigned long long)f2b(o[3]) << 48);
            *(unsigned long long*)&x2[orow + c0] = pv;
        }
    } else {
        float o[8][4];
        float mx = -3.0e38f;
        #pragma unroll
        for (int ct = 0; ct < 8; ++ct) {
            #pragma unroll
            for (int r = 0; r < 4; ++r) {
                float v = acc[ct][r] * zinv;
                v = v > 0.f ? v : __expf(v) - 1.f;
                o[ct][r] = v;
                mx = fmaxf(mx, v);
            }
        }
        mx = fmaxf(mx, __shfl_xor(mx, 16, 64));
        mx = fmaxf(mx, __shfl_xor(mx, 32, 64));
        float s = 0.f;
        #pragma unroll
        for (int ct = 0; ct < 8; ++ct)
            #pragma unroll
            for (int r = 0; r < 4; ++r) s += __expf(o[ct][r] - mx);
        s += __shfl_xor(s, 16, 64);
        s += __shfl_xor(s, 32, 64);
        float lse = mx + __logf(s);
        #pragma unroll
        for (int ct = 0; ct < 8; ++ct) {
            float4 st = {o[ct][0] - lse, o[ct][1] - lse, o[ct][2] - lse, o[ct][3] - lse};
            *(float4*)&dout[((size_t)(b * 512 + i)) * 128 + ct * 16 + g * 4] = st;
        }
    }
}

extern "C" void kernel_launch(void* const* d_in, const int* in_sizes, int n_in,
                              void* d_out, int out_size, void* d_ws, size_t ws_size,
                              hipStream_t stream)
{
    const float* hs = (const float*)d_in[0];
    const float* os = (const float*)d_in[1];
    const float* Wh = (const float*)d_in[4];
    const float* ah = (const float*)d_in[5];
    const float* Wo = (const float*)d_in[6];
    const float* ao = (const float*)d_in[7];
    float* out = (float*)d_out;

    u16t* h1T = (u16t*)d_ws;             // 4,194,304
    u16t* x2  = h1T + 4194304;           // 4,194,304
    u16t* h2T = x2 + 4194304;            // 1,048,576
    u16t* WhT = h2T + 1048576;           // 65,536
    u16t* WoT = WhT + 65536;             // 65,536
    u16t* xb  = WoT + 65536;             // 1,048,576
    float* f1a = (float*)(xb + 1048576); // 32,768
    float* f2a = f1a + 32768;
    float* f1b = f2a + 32768;            // 8,192
    float* f2b_ = f1b + 8192;

    prep_kernel<<<256, 256, 0, stream>>>(hs, os, Wh, Wo, WhT, WoT, xb);
    proj1_kernel<<<dim3(128, HEADS), 256, 0, stream>>>(xb, WhT, ah, h1T, f1a, f2a);
    attn_kernel<<<512, 256, 0, stream>>>(h1T, f1a, f2a, x2, nullptr, 0);
    proj2_kernel<<<128, 256, 0, stream>>>(x2, WoT, ao, h2T, f1b, f2b_);
    attn_kernel<<<64, 256, 0, stream>>>(h2T, f1b, f2b_, nullptr, out, 1);
}